// Round 8
// baseline (24.193 us; speedup 1.0000x reference)
//
#include <hip/hip_runtime.h>
#include <math.h>

#define G_N 1024
#define C_N 17
#define NX 200
#define NY 200
#define NZ 16
#define N_VOX (NX * NY * NZ)
#define MAHA_T 7.5f
#define CAP 128   // staged candidates per chunk (loop handles overflow)

// Fused kernel. Tile = 4(x) x 4(y) x 16(z) = 256 voxels, 256 threads,
// 1 voxel/thread. Wave w owns x-column X = bx*4+w (lane = yv*16+z).
// Small blocks -> low VGPR (one f[17]) -> 5-6 blocks/CU resident, so the
// epilogue HBM drain of one block overlaps cull/stage/compute of others.
__launch_bounds__(256, 4)
__global__ void gv_fused_kernel(const float* __restrict__ means,
                                const float* __restrict__ ops,
                                const float* __restrict__ feats,
                                const float* __restrict__ covs,
                                float* __restrict__ dens_out,
                                float* __restrict__ feat_out) {
    // Region A (17408 B), time-multiplexed:
    //   phase 1 (cull):     ushort s_stage[1024]           (2 KB)
    //   phase 2 (main):     float4 rows[CAP][8]            (16 KB)
    //   phase 3 (epilogue): per-wave out-stage 4 x 4352 B  (17408 B)
    __shared__ __align__(16) char smemA[4 * 64 * C_N * 4];
    __shared__ unsigned short s_list[G_N];
    __shared__ int s_wcnt[4];

    const int tid = threadIdx.x;
    const int wave = tid >> 6;
    const int lane = tid & 63;
    const int bx = blockIdx.x, by = blockIdx.y;

    // Block AABB (1.6m x 1.6m x full z)
    const float x0 = -40.f + (float)(bx * 4) * 0.4f;
    const float x1 = x0 + 1.6f;
    const float y0 = -40.f + (float)(by * 4) * 0.4f;
    const float y1 = y0 + 1.6f;

    // ---- Phase 1: 4-wave parallel cull from raw inputs (4 rounds/wave) ----
    unsigned short* s_stage = (unsigned short*)smemA;
    int base = 0;
#pragma unroll
    for (int r = 0; r < 4; ++r) {
        int g = wave * 256 + r * 64 + lane;
        float mx = means[3 * g], my = means[3 * g + 1], mz = means[3 * g + 2];
        float c00 = covs[9 * g], c11 = covs[9 * g + 4], c22 = covs[9 * g + 8];
        // exact ellipsoid AABB half-extent is sqrt(T*cov_ii); pad for fp safety
        float hx = sqrtf(MAHA_T * c00) * 1.01f + 0.01f;
        float hy = sqrtf(MAHA_T * c11) * 1.01f + 0.01f;
        float hz = sqrtf(MAHA_T * c22) * 1.01f + 0.01f;
        bool hit = (mx - hx <= x1) && (mx + hx >= x0) &&
                   (my - hy <= y1) && (my + hy >= y0) &&
                   (mz - hz <= 5.4f) && (mz + hz >= -1.0f);
        unsigned long long m = __ballot(hit);
        int rank = __popcll(m & ((1ull << lane) - 1ull));
        if (hit) s_stage[wave * 256 + base + rank] = (unsigned short)g;
        base += __popcll(m);
    }
    if (lane == 0) s_wcnt[wave] = base;
    __syncthreads();
    const int c0 = s_wcnt[0], c1 = s_wcnt[1], c2 = s_wcnt[2], c3 = s_wcnt[3];
    const int total = c0 + c1 + c2 + c3;
    int off = 0;
    if (wave > 0) off += c0;
    if (wave > 1) off += c1;
    if (wave > 2) off += c2;
    for (int i = lane; i < base; i += 64)          // wave-local segment copy
        s_list[off + i] = s_stage[wave * 256 + i]; // globally ascending-g order

    // ---- Voxel owned by this thread ----
    const int z = lane & 15;
    const int yv = lane >> 4;            // 0..3
    const int X = bx * 4 + wave;
    const int Y = by * 4 + yv;
    const long n00 = (long)16 * ((long)4 * by + (long)200 * X); // wave span start
    // (lane index == yv*16+z -> n00+lane is this thread's voxel)

    float cx, cy, cz;
    {
#pragma clang fp contract(off)   // bit-match ref: separate mul/add rounding
        cx = ((float)X + 0.5f) * 0.4f + -40.0f;
        cy = ((float)Y + 0.5f) * 0.4f + -40.0f;
        cz = ((float)z + 0.5f) * 0.4f + -1.0f;
    }

    float dsum = 0.f, cntf = 0.f;
    float fs[C_N];
#pragma unroll
    for (int c = 0; c < C_N; ++c) fs[c] = 0.f;

    // ---- Phase 2: stage survivors (fp64 inversion in-block) + main loop ----
    float4* s_gd = (float4*)smemA;
    for (int cb = 0; cb < total; cb += CAP) {
        const int nc = min(CAP, total - cb);
        __syncthreads();                 // region A free for reuse
        if (tid < nc) {                  // one thread per candidate
            int g = (int)s_list[cb + tid];
            const float* cv = covs + g * 9;
            double c00 = cv[0], c01 = cv[1], c02 = cv[2];
            double c11 = cv[4], c12 = cv[5], c22 = cv[8];
            double m00 = c11 * c22 - c12 * c12;
            double m01 = c02 * c12 - c01 * c22;
            double m02 = c01 * c12 - c02 * c11;
            double det = c00 * m00 + c01 * m01 + c02 * m02;
            double inv = 1.0 / det;
            float a00 = (float)(m00 * inv);
            float a01 = (float)(m01 * inv);
            float a02 = (float)(m02 * inv);
            float a11 = (float)((c00 * c22 - c02 * c02) * inv);
            float a12 = (float)((c02 * c01 - c00 * c12) * inv);
            float a22 = (float)((c00 * c11 - c01 * c01) * inv);
            float mx = means[3 * g], my = means[3 * g + 1], mz = means[3 * g + 2];
            float op = ops[g];
            const float* ft = feats + g * C_N;
            float4* o = s_gd + tid * 8;
            o[0] = make_float4(mx, my, mz, op);
            o[1] = make_float4(a00, a11, a22, 2.f * a01);
            o[2] = make_float4(2.f * a02, 2.f * a12, op * ft[0], op * ft[1]);
            o[3] = make_float4(op * ft[2], op * ft[3], op * ft[4], op * ft[5]);
            o[4] = make_float4(op * ft[6], op * ft[7], op * ft[8], op * ft[9]);
            o[5] = make_float4(op * ft[10], op * ft[11], op * ft[12], op * ft[13]);
            o[6] = make_float4(op * ft[14], op * ft[15], op * ft[16], 0.f);
        }
        __syncthreads();
        for (int j = 0; j < nc; ++j) {
            const float4* rowp = s_gd + j * 8;
            float4 q0 = rowp[0], q1 = rowp[1], q2 = rowp[2];
            float d0 = cx - q0.x, d1 = cy - q0.y, d2 = cz - q0.z;
            float u = fmaf(q1.x, d0, fmaf(q1.w, d1, q2.x * d2));
            float v = fmaf(q1.y, d1, q2.y * d2);
            float w = q1.z * d2;
            float maha = fmaf(d0, u, fmaf(d1, v, d2 * w));
            if (maha <= MAHA_T) {
                dsum = fmaf(q0.w, __expf(-0.5f * maha), dsum);
                cntf += 1.f;
                float4 q3 = rowp[3], q4 = rowp[4], q5 = rowp[5], q6 = rowp[6];
                fs[0] += q2.z;  fs[1] += q2.w;
                fs[2] += q3.x;  fs[3] += q3.y;  fs[4] += q3.z;  fs[5] += q3.w;
                fs[6] += q4.x;  fs[7] += q4.y;  fs[8] += q4.z;  fs[9] += q4.w;
                fs[10] += q5.x; fs[11] += q5.y; fs[12] += q5.z; fs[13] += q5.w;
                fs[14] += q6.x; fs[15] += q6.y; fs[16] += q6.z;
            }
        }
    }
    __syncthreads();   // all main-loop LDS reads done before out-stage reuse

    // ---- Phase 3: coalesced epilogue ----
    const float rd = 1.f / fmaxf(cntf, 1.f);
    dens_out[n00 + lane] = dsum * rd;   // 64 consecutive addrs per wave

    float* fw = (float*)(smemA + wave * (64 * C_N * 4));
#pragma unroll
    for (int c = 0; c < C_N; ++c) fw[lane * C_N + c] = fs[c] * rd;  // stride 17: conflict-free
    float4* gout = (float4*)(feat_out + n00 * C_N);   // 16B-aligned (n00 % 16 == 0)
    const float4* lsrc = (const float4*)fw;
#pragma unroll
    for (int r = 0; r < 4; ++r) gout[lane + 64 * r] = lsrc[lane + 64 * r];
    if (lane < 16) gout[256 + lane] = lsrc[256 + lane];  // 272 float4 = 64*17 floats
}

extern "C" void kernel_launch(void* const* d_in, const int* in_sizes, int n_in,
                              void* d_out, int out_size, void* d_ws, size_t ws_size,
                              hipStream_t stream) {
    const float* means3d     = (const float*)d_in[1];  // [1,G,3]
    const float* opacities   = (const float*)d_in[2];  // [1,G,1]
    const float* features    = (const float*)d_in[3];  // [1,G,C]
    const float* covariances = (const float*)d_in[4];  // [1,G,3,3]

    float* dens_out = (float*)d_out;             // [N]
    float* feat_out = (float*)d_out + N_VOX;     // [N,C]

    dim3 grid(NX / 4, NY / 4);
    gv_fused_kernel<<<grid, 256, 0, stream>>>(means3d, opacities, features,
                                              covariances, dens_out, feat_out);
}

// Round 9
// 20.446 us; speedup vs baseline: 1.1833x; 1.1833x over previous
//
#include <hip/hip_runtime.h>
#include <math.h>

#define G_N 1024
#define C_N 17
#define NX 200
#define NY 200
#define NZ 16
#define N_VOX (NX * NY * NZ)
#define MAHA_T 7.5f
#define CAP 128   // staged candidates per chunk (loop handles overflow)

// Fused kernel. Tile = 8(x) x 8(y) x 16(z) = 1024 voxels, 256 threads,
// 4 voxels/thread. Wave w owns x-columns X0=bx*8+2w and X1=X0+1; lane =
// yv*16+z owns (X0,Ya),(X0,Yb),(X1,Ya),(X1,Yb) with Ya=by*8+yv, Yb=Ya+4.
// Rationale: candidate rows are LDS-broadcast per wave; 4 voxels/thread
// amortizes the 7x ds_read_b128 per candidate over 4x more outputs.
__launch_bounds__(256, 2)
__global__ void gv_fused_kernel(const float* __restrict__ means,
                                const float* __restrict__ ops,
                                const float* __restrict__ feats,
                                const float* __restrict__ covs,
                                float* __restrict__ dens_out,
                                float* __restrict__ feat_out) {
    // Region A (17408 B), time-multiplexed:
    //   phase 1 (cull):     ushort s_stage[1024]           (2 KB)
    //   phase 2 (main):     float4 rows[CAP][7]            (14336 B)
    //   phase 3 (epilogue): per-wave out-stage 4 x 4352 B  (17408 B)
    __shared__ __align__(16) char smemA[4 * 64 * C_N * 4];
    __shared__ unsigned short s_list[G_N];
    __shared__ int s_wcnt[4];

    const int tid = threadIdx.x;
    const int wave = tid >> 6;
    const int lane = tid & 63;
    const int bx = blockIdx.x, by = blockIdx.y;

    // Block AABB (3.2m x 3.2m x full z)
    const float x0 = -40.f + (float)(bx * 8) * 0.4f;
    const float x1 = x0 + 3.2f;
    const float y0 = -40.f + (float)(by * 8) * 0.4f;
    const float y1 = y0 + 3.2f;

    // ---- Phase 1: 4-wave parallel cull from raw inputs (4 rounds/wave) ----
    unsigned short* s_stage = (unsigned short*)smemA;
    int base = 0;
#pragma unroll
    for (int r = 0; r < 4; ++r) {
        int g = wave * 256 + r * 64 + lane;
        float mx = means[3 * g], my = means[3 * g + 1], mz = means[3 * g + 2];
        float c00 = covs[9 * g], c11 = covs[9 * g + 4], c22 = covs[9 * g + 8];
        float hx = sqrtf(MAHA_T * c00) * 1.01f + 0.01f;
        float hy = sqrtf(MAHA_T * c11) * 1.01f + 0.01f;
        float hz = sqrtf(MAHA_T * c22) * 1.01f + 0.01f;
        bool hit = (mx - hx <= x1) && (mx + hx >= x0) &&
                   (my - hy <= y1) && (my + hy >= y0) &&
                   (mz - hz <= 5.4f) && (mz + hz >= -1.0f);
        unsigned long long m = __ballot(hit);
        int rank = __popcll(m & ((1ull << lane) - 1ull));
        if (hit) s_stage[wave * 256 + base + rank] = (unsigned short)g;
        base += __popcll(m);
    }
    if (lane == 0) s_wcnt[wave] = base;
    __syncthreads();
    const int c0 = s_wcnt[0], c1 = s_wcnt[1], c2 = s_wcnt[2], c3 = s_wcnt[3];
    const int total = c0 + c1 + c2 + c3;
    int off = 0;
    if (wave > 0) off += c0;
    if (wave > 1) off += c1;
    if (wave > 2) off += c2;
    for (int i = lane; i < base; i += 64)          // wave-local segment copy
        s_list[off + i] = s_stage[wave * 256 + i]; // globally ascending-g order

    // ---- Voxels owned by this thread ----
    const int z = lane & 15;
    const int yv = lane >> 4;            // 0..3
    const int X0 = bx * 8 + 2 * wave;
    const int X1 = X0 + 1;
    const int Ya = by * 8 + yv;          // second y at Ya+4

    float cx0, cx1, cya, cyb, cz;
    {
#pragma clang fp contract(off)   // bit-match ref: separate mul/add rounding
        cx0 = ((float)X0 + 0.5f) * 0.4f + -40.0f;
        cx1 = ((float)X1 + 0.5f) * 0.4f + -40.0f;
        cya = ((float)Ya + 0.5f) * 0.4f + -40.0f;
        cyb = ((float)(Ya + 4) + 0.5f) * 0.4f + -40.0f;
        cz  = ((float)z + 0.5f) * 0.4f + -1.0f;
    }

    // accumulators: a=(X0,Ya) b=(X0,Yb) c=(X1,Ya) d=(X1,Yb)
    float dsa = 0.f, dsb = 0.f, dsc = 0.f, dsd = 0.f;
    float cna = 0.f, cnb = 0.f, cnc = 0.f, cnd = 0.f;
    float fa[C_N], fb[C_N], fc[C_N], fd[C_N];
#pragma unroll
    for (int c = 0; c < C_N; ++c) { fa[c] = 0.f; fb[c] = 0.f; fc[c] = 0.f; fd[c] = 0.f; }

#define ACC(F, DS, CN, MH) { DS = fmaf(q0.w, __expf(-0.5f * (MH)), DS); CN += 1.f; \
    F[0] += q2.z;  F[1] += q2.w;  F[2] += q3.x;  F[3] += q3.y;  F[4] += q3.z; \
    F[5] += q3.w;  F[6] += q4.x;  F[7] += q4.y;  F[8] += q4.z;  F[9] += q4.w; \
    F[10] += q5.x; F[11] += q5.y; F[12] += q5.z; F[13] += q5.w; F[14] += q6.x; \
    F[15] += q6.y; F[16] += q6.z; }

    // ---- Phase 2: stage survivors (fp64 inversion in-block) + main loop ----
    float4* s_gd = (float4*)smemA;
    for (int cb = 0; cb < total; cb += CAP) {
        const int nc = min(CAP, total - cb);
        __syncthreads();                 // region A free for reuse
        if (tid < nc) {                  // one thread per candidate
            int g = (int)s_list[cb + tid];
            const float* cv = covs + g * 9;
            double c00 = cv[0], c01 = cv[1], c02 = cv[2];
            double c11 = cv[4], c12 = cv[5], c22 = cv[8];
            double m00 = c11 * c22 - c12 * c12;
            double m01 = c02 * c12 - c01 * c22;
            double m02 = c01 * c12 - c02 * c11;
            double det = c00 * m00 + c01 * m01 + c02 * m02;
            double inv = 1.0 / det;
            float a00 = (float)(m00 * inv);
            float a01 = (float)(m01 * inv);
            float a02 = (float)(m02 * inv);
            float a11 = (float)((c00 * c22 - c02 * c02) * inv);
            float a12 = (float)((c02 * c01 - c00 * c12) * inv);
            float a22 = (float)((c00 * c11 - c01 * c01) * inv);
            float mx = means[3 * g], my = means[3 * g + 1], mz = means[3 * g + 2];
            float op = ops[g];
            const float* ft = feats + g * C_N;
            float4* o = s_gd + tid * 7;
            o[0] = make_float4(mx, my, mz, op);
            o[1] = make_float4(a00, a11, a22, 2.f * a01);
            o[2] = make_float4(2.f * a02, 2.f * a12, op * ft[0], op * ft[1]);
            o[3] = make_float4(op * ft[2], op * ft[3], op * ft[4], op * ft[5]);
            o[4] = make_float4(op * ft[6], op * ft[7], op * ft[8], op * ft[9]);
            o[5] = make_float4(op * ft[10], op * ft[11], op * ft[12], op * ft[13]);
            o[6] = make_float4(op * ft[14], op * ft[15], op * ft[16], 0.f);
        }
        __syncthreads();
        for (int j = 0; j < nc; ++j) {
            const float4* rowp = s_gd + j * 7;
            float4 q0 = rowp[0], q1 = rowp[1], q2 = rowp[2];
            float d0a = cx0 - q0.x, d0b = cx1 - q0.x;
            float d1a = cya - q0.y, d1b = cyb - q0.y;
            float d2  = cz - q0.z;
            // shared subterms; per-voxel chains identical rounding to R3 form
            float s1 = q2.x * d2;        // (2a02)*d2
            float s2 = q2.y * d2;        // (2a12)*d2
            float w  = q1.z * d2;        // a22*d2
            float sw = d2 * w;
            float va = fmaf(q1.y, d1a, s2);
            float vb = fmaf(q1.y, d1b, s2);
            float ta = fmaf(d1a, va, sw);
            float tb = fmaf(d1b, vb, sw);
            float uaa = fmaf(q1.x, d0a, fmaf(q1.w, d1a, s1));
            float uab = fmaf(q1.x, d0a, fmaf(q1.w, d1b, s1));
            float uba = fmaf(q1.x, d0b, fmaf(q1.w, d1a, s1));
            float ubb = fmaf(q1.x, d0b, fmaf(q1.w, d1b, s1));
            float mA = fmaf(d0a, uaa, ta);
            float mB = fmaf(d0a, uab, tb);
            float mC = fmaf(d0b, uba, ta);
            float mD = fmaf(d0b, ubb, tb);
            bool ha = mA <= MAHA_T, hb = mB <= MAHA_T;
            bool hc = mC <= MAHA_T, hd = mD <= MAHA_T;
            if (ha | hb | hc | hd) {
                float4 q3 = rowp[3], q4 = rowp[4], q5 = rowp[5], q6 = rowp[6];
                if (ha) ACC(fa, dsa, cna, mA);
                if (hb) ACC(fb, dsb, cnb, mB);
                if (hc) ACC(fc, dsc, cnc, mC);
                if (hd) ACC(fd, dsd, cnd, mD);
            }
        }
    }
    __syncthreads();   // all main-loop LDS reads done before out-stage reuse

    // ---- Phase 3: coalesced epilogue, 4 passes (same-wave LDS in-order) ----
    float* fw = (float*)(smemA + wave * (64 * C_N * 4));
    const float4* lsrc = (const float4*)fw;

#define EPI(F, DS, CN, XX, HH) { \
    const float rd = 1.f / fmaxf(CN, 1.f); \
    const long nb = (long)16 * ((long)(by * 8 + 4 * (HH)) + 200L * (XX)); \
    dens_out[nb + lane] = DS * rd; \
    _Pragma("unroll") \
    for (int c = 0; c < C_N; ++c) fw[lane * C_N + c] = F[c] * rd; \
    float4* gout = (float4*)(feat_out + nb * C_N); \
    _Pragma("unroll") \
    for (int r = 0; r < 4; ++r) gout[lane + 64 * r] = lsrc[lane + 64 * r]; \
    if (lane < 16) gout[256 + lane] = lsrc[256 + lane]; }

    EPI(fa, dsa, cna, X0, 0);
    EPI(fb, dsb, cnb, X0, 1);
    EPI(fc, dsc, cnc, X1, 0);
    EPI(fd, dsd, cnd, X1, 1);
}

extern "C" void kernel_launch(void* const* d_in, const int* in_sizes, int n_in,
                              void* d_out, int out_size, void* d_ws, size_t ws_size,
                              hipStream_t stream) {
    const float* means3d     = (const float*)d_in[1];  // [1,G,3]
    const float* opacities   = (const float*)d_in[2];  // [1,G,1]
    const float* features    = (const float*)d_in[3];  // [1,G,C]
    const float* covariances = (const float*)d_in[4];  // [1,G,3,3]

    float* dens_out = (float*)d_out;             // [N]
    float* feat_out = (float*)d_out + N_VOX;     // [N,C]

    dim3 grid(NX / 8, NY / 8);
    gv_fused_kernel<<<grid, 256, 0, stream>>>(means3d, opacities, features,
                                              covariances, dens_out, feat_out);
}